// Round 6
// baseline (121.322 us; speedup 1.0000x reference)
//
#include <hip/hip_runtime.h>

// DWT db4, 6 levels, zero mode. x:[64, 262144] f32 ->
// concat(cA6, cD6, cD5, cD4, cD3, cD2, cD1) flat.
//
// R9 = R3 skeleton with ONE structural change: COALESCED detail stores.
// Previously every variant stored d[j] as scalar dwords with lanes at
// 16B stride (32 partial-line requests/instr). Now each wave writes its
// 64 chunks' d[] to a wave-private LDS scratch (stride-1, conflict-free),
// lgkmcnt, then 4 contiguous 256B stores (scratch read = 4-lane
// same-address broadcast, free). 16x fewer store instrs, ~13x fewer
// line requests on ~2/3 of all traffic.
// Also: L1 reads x directly from global (R8-proven; stage pass deleted),
// LDS 14.6KB -> 8 blocks/CU = 32 waves. Fast p in [1,126]; edge block
// handles p=0,127,128 (p=127 fast-path vector tail would read 4 floats
// past x; R8 lesson).

#define NT 256
#define TT 32

#define N0 262144
#define M1 131075
#define M2 65541
#define M3 32774
#define M4 16390
#define M5 8198
#define M6 4102

#define LEN0 2426
#define LEN1 1210
#define LEN2 602
#define LEN3 298
#define LEN4 146
#define LEN5 70

#define NC1 303
#define NC2 151
#define NC3 75
#define NC4 37
#define NC5 18

#define OFF_A6 ((size_t)0)
#define OFF_D6 ((size_t)262528)
#define OFF_D5 ((size_t)525056)
#define OFF_D4 ((size_t)1049728)
#define OFF_D3 ((size_t)2098688)
#define OFF_D2 ((size_t)4196224)
#define OFF_D1 ((size_t)8390848)

// fast-path LDS float layout (16B-aligned bases):
// W0E [0,608) W0O [608,1216)    cA1, then cA3, then cA5 (E/O halves)
// W1E [1216,1520) W1O [1520,1824) cA2, then cA4
// SCR [1824,2848)               4 waves x 256 floats detail-transpose
// slow path reuses lds flat: A [0,2432) B [2432,3648)
#define W0E 0
#define W0O 608
#define W1E 1216
#define W1O 1520
#define SCR 1824
#define LDS_FLOATS 3648

__device__ __constant__ float RLO[8] = {
    0.23037781330885523f, 0.7148465705525415f, 0.6308807679295904f,
    -0.02798376941698385f, -0.18703481171888114f, 0.030841381835986965f,
    0.032883011666982945f, -0.010597401784997278f};
__device__ __constant__ float RHI[8] = {
    -0.010597401784997278f, -0.032883011666982945f, 0.030841381835986965f,
    0.18703481171888114f, -0.02798376941698385f, -0.6308807679295904f,
    0.7148465705525415f, -0.23037781330885523f};

// wave-local LDS fence (scratch is wave-private; no s_barrier)
__device__ __forceinline__ void fence_wave() {
  asm volatile("s_waitcnt lgkmcnt(0)" ::: "memory");
}
// inter-level barrier: order LDS, sync waves; nt stores stay in flight
__device__ __forceinline__ void bar_lds() {
  asm volatile("s_waitcnt lgkmcnt(0)" ::: "memory");
  __builtin_amdgcn_s_barrier();
}

template <int SHIFT>
__device__ __forceinline__ void conv8(const float e[8], const float o[8],
                                      float a[4], float d[4]) {
#pragma unroll
  for (int j = 0; j < 4; ++j) {
    float aa = 0.f, dd = 0.f;
#pragma unroll
    for (int t = 0; t < 4; ++t) {
      float ev = e[j + t + SHIFT];
      float ov = o[j + t + SHIFT];
      aa = fmaf(RLO[2 * t], ev, aa);
      aa = fmaf(RLO[2 * t + 1], ov, aa);
      dd = fmaf(RHI[2 * t], ev, dd);
      dd = fmaf(RHI[2 * t + 1], ov, dd);
    }
    a[j] = aa;
    d[j] = dd;
  }
}

// flush this wave's 64 chunks of d[] (already in scrw) as 4 contiguous
// 256B stores. m = 64s+lane -> chunk m>>2, elem m&3 -> scrw[(m&3)*64+(m>>2)].
__device__ __forceinline__ void flush_d(const float* __restrict__ scrw,
                                        float* __restrict__ dg, int base,
                                        int LEN, int lane) {
#pragma unroll
  for (int s = 0; s < 4; ++s) {
    const int g = base + 64 * s + lane;
    if (g < LEN) {
      float v = scrw[(lane & 3) * 64 + 16 * s + (lane >> 2)];
      __builtin_nontemporal_store(v, dg + g);
    }
  }
}

// one mid level: E/O b128 reads -> cA to dE2/dO2 (float2), cD via
// scratch-transpose coalesced stores.
template <int LEN, int NC>
__device__ __forceinline__ void level_coal(const float4* __restrict__ sE4,
                                           const float4* __restrict__ sO4,
                                           float2* __restrict__ dE2,
                                           float2* __restrict__ dO2,
                                           float* __restrict__ dg,
                                           float* __restrict__ scrw, int wv,
                                           int lane) {
  for (int c0 = 0; c0 < NC; c0 += NT) {
    const int c = c0 + (wv << 6) + lane;
    if (c < NC) {
      float4 e0 = sE4[c], e1 = sE4[c + 1];
      float4 o0 = sO4[c], o1 = sO4[c + 1];
      float e[8] = {e0.x, e0.y, e0.z, e0.w, e1.x, e1.y, e1.z, e1.w};
      float o[8] = {o0.x, o0.y, o0.z, o0.w, o1.x, o1.y, o1.z, o1.w};
      float a[4], d[4];
      conv8<0>(e, o, a, d);
      dE2[c] = make_float2(a[0], a[2]);
      dO2[c] = make_float2(a[1], a[3]);
      scrw[lane] = d[0];
      scrw[64 + lane] = d[1];
      scrw[128 + lane] = d[2];
      scrw[192 + lane] = d[3];
    }
    fence_wave();
    flush_d(scrw, dg, 4 * c0 + (wv << 8), LEN, lane);
  }
}

// slow path (edge tiles): flat layout, bounds-checked (stores here are
// negligible volume; keep simple strided form)
__device__ inline void dwt_step_slow(const float* __restrict__ s,
                                     float* __restrict__ d, int base, int len,
                                     int M, int cOff, float* __restrict__ dglob,
                                     int tid) {
  for (int l = tid; l < len; l += NT) {
    int g = base + l;
    float a = 0.f, dt = 0.f;
    if (g >= 0 && g < M) {
#pragma unroll
      for (int m = 0; m < 8; ++m) {
        float v = s[2 * l + m];
        a = fmaf(RLO[m], v, a);
        dt = fmaf(RHI[m], v, dt);
      }
    }
    d[l] = a;
    if (l >= cOff && g < M) dglob[g] = dt;
  }
}

__global__ __launch_bounds__(NT, 8) void dwt6_kernel(
    const float* __restrict__ x, float* __restrict__ out) {
  const int px = blockIdx.x;
  const int row = blockIdx.y;
  const int tid = threadIdx.x;
  const int wv = tid >> 6;
  const int lane = tid & 63;

  __shared__ __align__(16) float lds[LDS_FLOATS];

  const float* __restrict__ xr = x + (size_t)row * N0;
  const size_t r1 = (size_t)row * M1, r2 = (size_t)row * M2,
               r3 = (size_t)row * M3, r4 = (size_t)row * M4,
               r5 = (size_t)row * M5, r6 = (size_t)row * M6;

  if (px < 126) {
    // ---- fast path: tile p in [1,126]; all reads provably in-bounds ----
    const int p = px + 1;
    const int b6 = p * TT;
    const int b5 = 2 * b6 - 6;
    const int b4 = 2 * b5 - 6;
    const int b3 = 2 * b4 - 6;
    const int b2 = 2 * b3 - 6;
    const int b1 = 2 * b2 - 6;  // 1024p - 186

    float2* w0E2 = (float2*)(lds + W0E);
    float2* w0O2 = (float2*)(lds + W0O);
    float2* w1E2 = (float2*)(lds + W1E);
    float2* w1O2 = (float2*)(lds + W1O);
    const float4* w0E4 = (const float4*)(lds + W0E);
    const float4* w0O4 = (const float4*)(lds + W0O);
    const float4* w1E4 = (const float4*)(lds + W1E);
    const float4* w1O4 = (const float4*)(lds + W1O);
    float* __restrict__ scrw = lds + SCR + (wv << 8);

    // ---- level 1: x direct from global -> W0 + coalesced cD1 ----
    {
      const float4* __restrict__ x4 = (const float4*)(xr + (2048 * p - 380));
      float* __restrict__ dg = out + OFF_D1 + r1 + b1;
      for (int c0 = 0; c0 < NC1; c0 += NT) {
        const int c = c0 + (wv << 6) + lane;
        if (c < NC1) {
          float4 q0 = x4[2 * c], q1 = x4[2 * c + 1];
          float4 q2 = x4[2 * c + 2], q3 = x4[2 * c + 3];
          float e[8] = {q0.x, q0.z, q1.x, q1.z, q2.x, q2.z, q3.x, q3.z};
          float o[8] = {q0.y, q0.w, q1.y, q1.w, q2.y, q2.w, q3.y, q3.w};
          float a[4], d[4];
          conv8<1>(e, o, a, d);
          w0E2[c] = make_float2(a[0], a[2]);
          w0O2[c] = make_float2(a[1], a[3]);
          scrw[lane] = d[0];
          scrw[64 + lane] = d[1];
          scrw[128 + lane] = d[2];
          scrw[192 + lane] = d[3];
        }
        fence_wave();
        flush_d(scrw, dg, 4 * c0 + (wv << 8), LEN1, lane);
      }
    }
    bar_lds();

    level_coal<LEN2, NC2>(w0E4, w0O4, w1E2, w1O2, out + OFF_D2 + r2 + b2,
                          scrw, wv, lane);
    bar_lds();
    level_coal<LEN3, NC3>(w1E4, w1O4, w0E2, w0O2, out + OFF_D3 + r3 + b3,
                          scrw, wv, lane);
    bar_lds();
    level_coal<LEN4, NC4>(w0E4, w0O4, w1E2, w1O2, out + OFF_D4 + r4 + b4,
                          scrw, wv, lane);
    bar_lds();
    level_coal<LEN5, NC5>(w1E4, w1O4, w0E2, w0O2, out + OFF_D5 + r5 + b5,
                          scrw, wv, lane);
    bar_lds();

    // ---- level 6: 32 outputs from W0 (cA5), via wave-0 scratch ----
    {
      float* __restrict__ ga = out + OFF_A6 + r6 + b6;
      float* __restrict__ gd = out + OFF_D6 + r6 + b6;
      float* __restrict__ scr0 = lds + SCR;
      if (tid < 8) {
        const int c = tid;
        float4 e0 = w0E4[c], e1 = w0E4[c + 1];
        float4 o0 = w0O4[c], o1 = w0O4[c + 1];
        float e[8] = {e0.x, e0.y, e0.z, e0.w, e1.x, e1.y, e1.z, e1.w};
        float o[8] = {o0.x, o0.y, o0.z, o0.w, o1.x, o1.y, o1.z, o1.w};
        float a[4], d[4];
        conv8<0>(e, o, a, d);
#pragma unroll
        for (int j = 0; j < 4; ++j) {
          scr0[j * 64 + c] = a[j];
          scr0[j * 64 + 8 + c] = d[j];
        }
      }
      fence_wave();
      if (tid < 32) {
        float va = scr0[(tid & 3) * 64 + (tid >> 2)];
        float vd = scr0[(tid & 3) * 64 + 8 + (tid >> 2)];
        __builtin_nontemporal_store(va, ga + tid);
        __builtin_nontemporal_store(vd, gd + tid);
      }
    }
  } else {
    // ---- edge block: tiles p = 0, 127, 128 (slow, cooperative) ----
    float* A = lds;          // LEN0 = 2426 <= 2432
    float* B = lds + 2432;   // LEN1 = 1210 <= 1216
#pragma unroll 1
    for (int t = 0; t < 3; ++t) {
      const int p = (t == 0) ? 0 : (t == 1) ? 127 : 128;
      const int b6 = p * TT;
      const int b5 = 2 * b6 - 6;
      const int b4 = 2 * b5 - 6;
      const int b3 = 2 * b4 - 6;
      const int b2 = 2 * b3 - 6;
      const int b1 = 2 * b2 - 6;
      const int b0 = 2 * b1 - 6;  // 2048p - 378
      const int c1 = (p == 0) ? 186 : 0;
      const int c2 = (p == 0) ? 90 : 0;
      const int c3 = (p == 0) ? 42 : 0;
      const int c4 = (p == 0) ? 18 : 0;
      const int c5 = (p == 0) ? 6 : 0;

      __syncthreads();  // protect A/B reuse across tiles
      for (int l = tid; l < LEN0; l += NT) {
        int g = b0 + l;
        A[l] = (g >= 0 && g < N0) ? xr[g] : 0.0f;
      }
      __syncthreads();

      dwt_step_slow(A, B, b1, LEN1, M1, c1, out + OFF_D1 + r1, tid);
      __syncthreads();
      dwt_step_slow(B, A, b2, LEN2, M2, c2, out + OFF_D2 + r2, tid);
      __syncthreads();
      dwt_step_slow(A, B, b3, LEN3, M3, c3, out + OFF_D3 + r3, tid);
      __syncthreads();
      dwt_step_slow(B, A, b4, LEN4, M4, c4, out + OFF_D4 + r4, tid);
      __syncthreads();
      dwt_step_slow(A, B, b5, LEN5, M5, c5, out + OFF_D5 + r5, tid);
      __syncthreads();

      for (int l = tid; l < TT; l += NT) {
        int g = b6 + l;
        if (g < M6) {
          float a = 0.f, dt = 0.f;
#pragma unroll
          for (int m = 0; m < 8; ++m) {
            float v = B[2 * l + m];
            a = fmaf(RLO[m], v, a);
            dt = fmaf(RHI[m], v, dt);
          }
          out[OFF_A6 + r6 + g] = a;
          out[OFF_D6 + r6 + g] = dt;
        }
      }
    }
  }
}

extern "C" void kernel_launch(void* const* d_in, const int* in_sizes, int n_in,
                              void* d_out, int out_size, void* d_ws,
                              size_t ws_size, hipStream_t stream) {
  const float* x = (const float*)d_in[0];
  float* out = (float*)d_out;
  dim3 grid(127, 64);  // 126 fast tiles (p=1..126) + 1 edge block (p=0,127,128)
  dwt6_kernel<<<grid, NT, 0, stream>>>(x, out);
}

// Round 7
// 120.234 us; speedup vs baseline: 1.0090x; 1.0090x over previous
//
#include <hip/hip_runtime.h>

// DWT db4, 6 levels, zero mode. x:[64, 262144] f32 ->
// concat(cA6, cD6, cD5, cD4, cD3, cD2, cD1) flat.
//
// R10 = EXACT round-0 R3 kernel (best measured: 43.0us) with ONE change:
// all output stores switched from __builtin_nontemporal_store (no-allocate
// -> forced HBM writes inside our own window, contending with the
// harness re-poison's L3 writeback drain) to PLAIN stores (write-allocate
// in L2/L3; out = 67MB fits the 256MB L3, flush deferred past our
// window). Single-variable A/B vs R3.

#define NT 256
#define TT 32
#define LEN0 2426  // 64*TT + 378
#define LEN1 1210
#define LEN2 602
#define LEN3 298
#define LEN4 146
#define LEN5 70

#define N0 262144
#define M1 131075
#define M2 65541
#define M3 32774
#define M4 16390
#define M5 8198
#define M6 4102

#define OFF_A6 ((size_t)0)
#define OFF_D6 ((size_t)262528)
#define OFF_D5 ((size_t)525056)
#define OFF_D4 ((size_t)1049728)
#define OFF_D3 ((size_t)2098688)
#define OFF_D2 ((size_t)4196224)
#define OFF_D1 ((size_t)8390848)

// LDS float layout: A-E [0,1216) A-O [1216,2432) B-E [2432,3040) B-O [3040,3648)
#define AE 0
#define AO 1216
#define BE 2432
#define BO 3040
#define LDS_FLOATS 3648

__device__ __constant__ float RLO[8] = {
    0.23037781330885523f, 0.7148465705525415f, 0.6308807679295904f,
    -0.02798376941698385f, -0.18703481171888114f, 0.030841381835986965f,
    0.032883011666982945f, -0.010597401784997278f};
__device__ __constant__ float RHI[8] = {
    -0.010597401784997278f, -0.032883011666982945f, 0.030841381835986965f,
    0.18703481171888114f, -0.02798376941698385f, -0.6308807679295904f,
    0.7148465705525415f, -0.23037781330885523f};

// One fast level: src de-interleaved (sE4/sO4), dst de-interleaved
// (dE2/dO2), details -> dg (global, PLAIN stores). SHIFT=1 for level 1
// (staged buffer starts 2 before the window base), 0 otherwise.
template <int LEN, int NC, int SHIFT>
__device__ __forceinline__ void level_fast(const float4* __restrict__ sE4,
                                           const float4* __restrict__ sO4,
                                           float2* __restrict__ dE2,
                                           float2* __restrict__ dO2,
                                           float* __restrict__ dg) {
  for (int c = threadIdx.x; c < NC; c += NT) {
    float4 e0 = sE4[c], e1 = sE4[c + 1];
    float4 o0 = sO4[c], o1 = sO4[c + 1];
    float e[8] = {e0.x, e0.y, e0.z, e0.w, e1.x, e1.y, e1.z, e1.w};
    float o[8] = {o0.x, o0.y, o0.z, o0.w, o1.x, o1.y, o1.z, o1.w};
    float a[4], d[4];
#pragma unroll
    for (int j = 0; j < 4; ++j) {
      float aa = 0.f, dd = 0.f;
#pragma unroll
      for (int t = 0; t < 4; ++t) {
        float ev = e[j + t + SHIFT];
        float ov = o[j + t + SHIFT];
        aa = fmaf(RLO[2 * t], ev, aa);
        aa = fmaf(RLO[2 * t + 1], ov, aa);
        dd = fmaf(RHI[2 * t], ev, dd);
        dd = fmaf(RHI[2 * t + 1], ov, dd);
      }
      a[j] = aa;
      d[j] = dd;
    }
    dE2[c] = make_float2(a[0], a[2]);
    dO2[c] = make_float2(a[1], a[3]);
    const int l0 = 4 * c;
    if (l0 + 4 <= LEN) {
#pragma unroll
      for (int j = 0; j < 4; ++j) dg[l0 + j] = d[j];
    } else {
#pragma unroll
      for (int j = 0; j < 4; ++j)
        if (l0 + j < LEN) dg[l0 + j] = d[j];
    }
  }
}

// slow path (edge tiles): flat layout, bounds-checked
__device__ inline void dwt_step_slow(const float* __restrict__ s,
                                     float* __restrict__ d, int base, int len,
                                     int M, int cOff, float* __restrict__ dglob,
                                     int tid) {
  for (int l = tid; l < len; l += NT) {
    int g = base + l;
    float a = 0.f, dt = 0.f;
    if (g >= 0 && g < M) {
#pragma unroll
      for (int m = 0; m < 8; ++m) {
        float v = s[2 * l + m];
        a = fmaf(RLO[m], v, a);
        dt = fmaf(RHI[m], v, dt);
      }
    }
    d[l] = a;
    if (l >= cOff && g < M) dglob[g] = dt;
  }
}

__global__ __launch_bounds__(NT, 8) void dwt6_kernel(const float* __restrict__ x,
                                                     float* __restrict__ out) {
  const int p = blockIdx.x;
  const int row = blockIdx.y;
  const int tid = threadIdx.x;

  __shared__ float lds[LDS_FLOATS];

  const int b6 = p * TT;
  const int b5 = 2 * b6 - 6;
  const int b4 = 2 * b5 - 6;
  const int b3 = 2 * b4 - 6;
  const int b2 = 2 * b3 - 6;
  const int b1 = 2 * b2 - 6;
  const int b0 = 2 * b1 - 6;  // 2048p - 378

  const size_t r1 = (size_t)row * M1, r2 = (size_t)row * M2,
               r3 = (size_t)row * M3, r4 = (size_t)row * M4,
               r5 = (size_t)row * M5, r6 = (size_t)row * M6;

  if (p >= 1 && p <= 127) {
    // ---- fast path: all levels provably in-bounds ----
    // stage x[sb .. sb+2427], sb = b0-2 (== 0 mod 4) into A (de-interleaved)
    const float4* __restrict__ xs4 =
        (const float4*)(x + (size_t)row * N0 + (b0 - 2));
    float2* __restrict__ aE2 = (float2*)(lds + AE);
    float2* __restrict__ aO2 = (float2*)(lds + AO);
    for (int m = tid; m < 607; m += NT) {
      float4 v = xs4[m];
      aE2[m] = make_float2(v.x, v.z);
      aO2[m] = make_float2(v.y, v.w);
    }
    __syncthreads();

    const float4* aE4 = (const float4*)(lds + AE);
    const float4* aO4 = (const float4*)(lds + AO);
    const float4* bE4 = (const float4*)(lds + BE);
    const float4* bO4 = (const float4*)(lds + BO);
    float2* bE2 = (float2*)(lds + BE);
    float2* bO2 = (float2*)(lds + BO);

    level_fast<LEN1, 303, 1>(aE4, aO4, bE2, bO2, out + OFF_D1 + r1 + b1);
    __syncthreads();
    level_fast<LEN2, 151, 0>(bE4, bO4, aE2, aO2, out + OFF_D2 + r2 + b2);
    __syncthreads();
    level_fast<LEN3, 75, 0>(aE4, aO4, bE2, bO2, out + OFF_D3 + r3 + b3);
    __syncthreads();
    level_fast<LEN4, 37, 0>(bE4, bO4, aE2, aO2, out + OFF_D4 + r4 + b4);
    __syncthreads();
    level_fast<LEN5, 18, 0>(aE4, aO4, bE2, bO2, out + OFF_D5 + r5 + b5);
    __syncthreads();

    // level 6: 32 outputs, 8 chunks, straight to global
    float* __restrict__ ga = out + OFF_A6 + r6 + b6;
    float* __restrict__ gd = out + OFF_D6 + r6 + b6;
    for (int c = tid; c < 8; c += NT) {
      float4 e0 = bE4[c], e1 = bE4[c + 1];
      float4 o0 = bO4[c], o1 = bO4[c + 1];
      float e[8] = {e0.x, e0.y, e0.z, e0.w, e1.x, e1.y, e1.z, e1.w};
      float o[8] = {o0.x, o0.y, o0.z, o0.w, o1.x, o1.y, o1.z, o1.w};
#pragma unroll
      for (int j = 0; j < 4; ++j) {
        float aa = 0.f, dd = 0.f;
#pragma unroll
        for (int t = 0; t < 4; ++t) {
          aa = fmaf(RLO[2 * t], e[j + t], aa);
          aa = fmaf(RLO[2 * t + 1], o[j + t], aa);
          dd = fmaf(RHI[2 * t], e[j + t], dd);
          dd = fmaf(RHI[2 * t + 1], o[j + t], dd);
        }
        ga[4 * c + j] = aa;
        gd[4 * c + j] = dd;
      }
    }
  } else {
    // ---- slow path: p == 0 or p == 128 ----
    float* bufA = lds;         // LEN0 = 2426 <= 2432
    float* bufB = lds + BE;    // LEN1 = 1210 <= 1216
    const float* __restrict__ xr = x + (size_t)row * N0;
    for (int l = tid; l < LEN0; l += NT) {
      int g = b0 + l;
      bufA[l] = (g >= 0 && g < N0) ? xr[g] : 0.0f;
    }
    __syncthreads();

    dwt_step_slow(bufA, bufB, b1, LEN1, M1, 186, out + OFF_D1 + r1, tid);
    __syncthreads();
    dwt_step_slow(bufB, bufA, b2, LEN2, M2, 90, out + OFF_D2 + r2, tid);
    __syncthreads();
    dwt_step_slow(bufA, bufB, b3, LEN3, M3, 42, out + OFF_D3 + r3, tid);
    __syncthreads();
    dwt_step_slow(bufB, bufA, b4, LEN4, M4, 18, out + OFF_D4 + r4, tid);
    __syncthreads();
    dwt_step_slow(bufA, bufB, b5, LEN5, M5, 6, out + OFF_D5 + r5, tid);
    __syncthreads();

    for (int l = tid; l < TT; l += NT) {
      int g = b6 + l;
      if (g < M6) {
        float a = 0.f, dt = 0.f;
#pragma unroll
        for (int m = 0; m < 8; ++m) {
          float v = bufB[2 * l + m];
          a = fmaf(RLO[m], v, a);
          dt = fmaf(RHI[m], v, dt);
        }
        out[OFF_A6 + r6 + g] = a;
        out[OFF_D6 + r6 + g] = dt;
      }
    }
  }
}

extern "C" void kernel_launch(void* const* d_in, const int* in_sizes, int n_in,
                              void* d_out, int out_size, void* d_ws,
                              size_t ws_size, hipStream_t stream) {
  const float* x = (const float*)d_in[0];
  float* out = (float*)d_out;
  dim3 grid(129, 64);  // 129 tiles of 32 level-6 outputs cover M6=4102
  dwt6_kernel<<<grid, NT, 0, stream>>>(x, out);
}

// Round 8
// 115.262 us; speedup vs baseline: 1.0526x; 1.0431x over previous
//
#include <hip/hip_runtime.h>

// DWT db4, 6 levels, zero mode. x:[64, 262144] f32 ->
// concat(cA6, cD6, cD5, cD4, cD3, cD2, cD1) flat.
//
// R11 = revert to the best-scored kernel (round-0 R3, 113.9/116.3 us).
// Session conclusion: the scored iteration's traffic is conserved
// (268MB poison + ~120MB ours); nt stores pay the output writeback
// INSIDE our compute window where it overlaps (optimal for score),
// plain stores defer it into the serial fill window (R10: kernel <41us
// but score +4). Ten schedule variants bounded the kernel at 43-55us
// with all visible counters behaving as predicted -> effective roofline.
//
// R3: TT=32 tiles (8 blocks/CU = 32 waves, 100% occupancy cap),
// de-interleaved even/odd LDS layout (all LDS reads stride-1 b128,
// writes stride-1 b64), float4 staging, non-temporal output stores.
// Interior tiles p=1..127 fast path; p=0,128 bounds-checked slow path.

#define NT 256
#define TT 32
#define LEN0 2426  // 64*TT + 378
#define LEN1 1210
#define LEN2 602
#define LEN3 298
#define LEN4 146
#define LEN5 70

#define N0 262144
#define M1 131075
#define M2 65541
#define M3 32774
#define M4 16390
#define M5 8198
#define M6 4102

#define OFF_A6 ((size_t)0)
#define OFF_D6 ((size_t)262528)
#define OFF_D5 ((size_t)525056)
#define OFF_D4 ((size_t)1049728)
#define OFF_D3 ((size_t)2098688)
#define OFF_D2 ((size_t)4196224)
#define OFF_D1 ((size_t)8390848)

// LDS float layout: A-E [0,1216) A-O [1216,2432) B-E [2432,3040) B-O [3040,3648)
#define AE 0
#define AO 1216
#define BE 2432
#define BO 3040
#define LDS_FLOATS 3648

__device__ __constant__ float RLO[8] = {
    0.23037781330885523f, 0.7148465705525415f, 0.6308807679295904f,
    -0.02798376941698385f, -0.18703481171888114f, 0.030841381835986965f,
    0.032883011666982945f, -0.010597401784997278f};
__device__ __constant__ float RHI[8] = {
    -0.010597401784997278f, -0.032883011666982945f, 0.030841381835986965f,
    0.18703481171888114f, -0.02798376941698385f, -0.6308807679295904f,
    0.7148465705525415f, -0.23037781330885523f};

// One fast level: src de-interleaved (sE4/sO4), dst de-interleaved
// (dE2/dO2), details -> dg (global, nontemporal). SHIFT=1 for level 1
// (staged buffer starts 2 before the window base), 0 otherwise.
template <int LEN, int NC, int SHIFT>
__device__ __forceinline__ void level_fast(const float4* __restrict__ sE4,
                                           const float4* __restrict__ sO4,
                                           float2* __restrict__ dE2,
                                           float2* __restrict__ dO2,
                                           float* __restrict__ dg) {
  for (int c = threadIdx.x; c < NC; c += NT) {
    float4 e0 = sE4[c], e1 = sE4[c + 1];
    float4 o0 = sO4[c], o1 = sO4[c + 1];
    float e[8] = {e0.x, e0.y, e0.z, e0.w, e1.x, e1.y, e1.z, e1.w};
    float o[8] = {o0.x, o0.y, o0.z, o0.w, o1.x, o1.y, o1.z, o1.w};
    float a[4], d[4];
#pragma unroll
    for (int j = 0; j < 4; ++j) {
      float aa = 0.f, dd = 0.f;
#pragma unroll
      for (int t = 0; t < 4; ++t) {
        float ev = e[j + t + SHIFT];
        float ov = o[j + t + SHIFT];
        aa = fmaf(RLO[2 * t], ev, aa);
        aa = fmaf(RLO[2 * t + 1], ov, aa);
        dd = fmaf(RHI[2 * t], ev, dd);
        dd = fmaf(RHI[2 * t + 1], ov, dd);
      }
      a[j] = aa;
      d[j] = dd;
    }
    dE2[c] = make_float2(a[0], a[2]);
    dO2[c] = make_float2(a[1], a[3]);
    const int l0 = 4 * c;
    if (l0 + 4 <= LEN) {
#pragma unroll
      for (int j = 0; j < 4; ++j) __builtin_nontemporal_store(d[j], dg + l0 + j);
    } else {
#pragma unroll
      for (int j = 0; j < 4; ++j)
        if (l0 + j < LEN) __builtin_nontemporal_store(d[j], dg + l0 + j);
    }
  }
}

// slow path (edge tiles): flat layout, bounds-checked
__device__ inline void dwt_step_slow(const float* __restrict__ s,
                                     float* __restrict__ d, int base, int len,
                                     int M, int cOff, float* __restrict__ dglob,
                                     int tid) {
  for (int l = tid; l < len; l += NT) {
    int g = base + l;
    float a = 0.f, dt = 0.f;
    if (g >= 0 && g < M) {
#pragma unroll
      for (int m = 0; m < 8; ++m) {
        float v = s[2 * l + m];
        a = fmaf(RLO[m], v, a);
        dt = fmaf(RHI[m], v, dt);
      }
    }
    d[l] = a;
    if (l >= cOff && g < M) dglob[g] = dt;
  }
}

__global__ __launch_bounds__(NT, 8) void dwt6_kernel(const float* __restrict__ x,
                                                     float* __restrict__ out) {
  const int p = blockIdx.x;
  const int row = blockIdx.y;
  const int tid = threadIdx.x;

  __shared__ float lds[LDS_FLOATS];

  const int b6 = p * TT;
  const int b5 = 2 * b6 - 6;
  const int b4 = 2 * b5 - 6;
  const int b3 = 2 * b4 - 6;
  const int b2 = 2 * b3 - 6;
  const int b1 = 2 * b2 - 6;
  const int b0 = 2 * b1 - 6;  // 2048p - 378

  const size_t r1 = (size_t)row * M1, r2 = (size_t)row * M2,
               r3 = (size_t)row * M3, r4 = (size_t)row * M4,
               r5 = (size_t)row * M5, r6 = (size_t)row * M6;

  if (p >= 1 && p <= 127) {
    // ---- fast path: all levels provably in-bounds ----
    // stage x[sb .. sb+2427], sb = b0-2 (== 0 mod 4) into A (de-interleaved)
    const float4* __restrict__ xs4 =
        (const float4*)(x + (size_t)row * N0 + (b0 - 2));
    float2* __restrict__ aE2 = (float2*)(lds + AE);
    float2* __restrict__ aO2 = (float2*)(lds + AO);
    for (int m = tid; m < 607; m += NT) {
      float4 v = xs4[m];
      aE2[m] = make_float2(v.x, v.z);
      aO2[m] = make_float2(v.y, v.w);
    }
    __syncthreads();

    const float4* aE4 = (const float4*)(lds + AE);
    const float4* aO4 = (const float4*)(lds + AO);
    const float4* bE4 = (const float4*)(lds + BE);
    const float4* bO4 = (const float4*)(lds + BO);
    float2* bE2 = (float2*)(lds + BE);
    float2* bO2 = (float2*)(lds + BO);

    level_fast<LEN1, 303, 1>(aE4, aO4, bE2, bO2, out + OFF_D1 + r1 + b1);
    __syncthreads();
    level_fast<LEN2, 151, 0>(bE4, bO4, aE2, aO2, out + OFF_D2 + r2 + b2);
    __syncthreads();
    level_fast<LEN3, 75, 0>(aE4, aO4, bE2, bO2, out + OFF_D3 + r3 + b3);
    __syncthreads();
    level_fast<LEN4, 37, 0>(bE4, bO4, aE2, aO2, out + OFF_D4 + r4 + b4);
    __syncthreads();
    level_fast<LEN5, 18, 0>(aE4, aO4, bE2, bO2, out + OFF_D5 + r5 + b5);
    __syncthreads();

    // level 6: 32 outputs, 8 chunks, straight to global
    float* __restrict__ ga = out + OFF_A6 + r6 + b6;
    float* __restrict__ gd = out + OFF_D6 + r6 + b6;
    for (int c = tid; c < 8; c += NT) {
      float4 e0 = bE4[c], e1 = bE4[c + 1];
      float4 o0 = bO4[c], o1 = bO4[c + 1];
      float e[8] = {e0.x, e0.y, e0.z, e0.w, e1.x, e1.y, e1.z, e1.w};
      float o[8] = {o0.x, o0.y, o0.z, o0.w, o1.x, o1.y, o1.z, o1.w};
#pragma unroll
      for (int j = 0; j < 4; ++j) {
        float aa = 0.f, dd = 0.f;
#pragma unroll
        for (int t = 0; t < 4; ++t) {
          aa = fmaf(RLO[2 * t], e[j + t], aa);
          aa = fmaf(RLO[2 * t + 1], o[j + t], aa);
          dd = fmaf(RHI[2 * t], e[j + t], dd);
          dd = fmaf(RHI[2 * t + 1], o[j + t], dd);
        }
        __builtin_nontemporal_store(aa, ga + 4 * c + j);
        __builtin_nontemporal_store(dd, gd + 4 * c + j);
      }
    }
  } else {
    // ---- slow path: p == 0 or p == 128 ----
    float* bufA = lds;         // LEN0 = 2426 <= 2432
    float* bufB = lds + BE;    // LEN1 = 1210 <= 1216
    const float* __restrict__ xr = x + (size_t)row * N0;
    for (int l = tid; l < LEN0; l += NT) {
      int g = b0 + l;
      bufA[l] = (g >= 0 && g < N0) ? xr[g] : 0.0f;
    }
    __syncthreads();

    dwt_step_slow(bufA, bufB, b1, LEN1, M1, 186, out + OFF_D1 + r1, tid);
    __syncthreads();
    dwt_step_slow(bufB, bufA, b2, LEN2, M2, 90, out + OFF_D2 + r2, tid);
    __syncthreads();
    dwt_step_slow(bufA, bufB, b3, LEN3, M3, 42, out + OFF_D3 + r3, tid);
    __syncthreads();
    dwt_step_slow(bufB, bufA, b4, LEN4, M4, 18, out + OFF_D4 + r4, tid);
    __syncthreads();
    dwt_step_slow(bufA, bufB, b5, LEN5, M5, 6, out + OFF_D5 + r5, tid);
    __syncthreads();

    for (int l = tid; l < TT; l += NT) {
      int g = b6 + l;
      if (g < M6) {
        float a = 0.f, dt = 0.f;
#pragma unroll
        for (int m = 0; m < 8; ++m) {
          float v = bufB[2 * l + m];
          a = fmaf(RLO[m], v, a);
          dt = fmaf(RHI[m], v, dt);
        }
        out[OFF_A6 + r6 + g] = a;
        out[OFF_D6 + r6 + g] = dt;
      }
    }
  }
}

extern "C" void kernel_launch(void* const* d_in, const int* in_sizes, int n_in,
                              void* d_out, int out_size, void* d_ws,
                              size_t ws_size, hipStream_t stream) {
  const float* x = (const float*)d_in[0];
  float* out = (float*)d_out;
  dim3 grid(129, 64);  // 129 tiles of 32 level-6 outputs cover M6=4102
  dwt6_kernel<<<grid, NT, 0, stream>>>(x, out);
}